// Round 7
// baseline (4327.898 us; speedup 1.0000x reference)
//
#include <hip/hip_runtime.h>
#include <hip/hip_bf16.h>
#include <math.h>

#define B_SZ 16384
#define T_CONV 8
#define HID 256
#define SK 16   // split-K slices for the weight-collapse GEMMs

typedef __bf16 bf16x8 __attribute__((ext_vector_type(8)));
typedef float f32x4 __attribute__((ext_vector_type(4)));

__device__ __forceinline__ float fsigm(float x) { return 1.f / (1.f + __expf(-x)); }
__device__ __forceinline__ float ftanh(float x) {
    float t = __expf(-2.f * fabsf(x));
    float r = (1.f - t) / (1.f + t);
    return x >= 0.f ? r : -r;
}

// ---------------------------------------------------------------------------
// Feature kernel: embeddings -> nv -> conv(elu) -> Xp (B*8, 64) bf16, padded
// ---------------------------------------------------------------------------
#define FB_SAMPLES 4
__global__ __launch_bounds__(256) void feature_kernel(
    const int* __restrict__ region_idx, const int* __restrict__ poi_idx,
    const int* __restrict__ car_idx, const int* __restrict__ week_idx,
    const int* __restrict__ time_idx, const float* __restrict__ coords,
    const float* __restrict__ region_tbl, const float* __restrict__ poi_tbl,
    const float* __restrict__ car_tbl, const float* __restrict__ week_tbl,
    const float* __restrict__ time_tbl, const float* __restrict__ W_rp,
    const float* __restrict__ b_rp, const float* __restrict__ W_co,
    const float* __restrict__ b_co, const float* __restrict__ conv_w,
    const float* __restrict__ conv_b, __bf16* __restrict__ Xp)
{
    __shared__ float s_cw[3 * 40 * 32];
    __shared__ float s_nv[FB_SAMPLES][10][40];
    __shared__ float s_emb[FB_SAMPLES][27];
    __shared__ float s_rp[FB_SAMPLES][10][12];

    int tid = threadIdx.x;
    for (int i = tid; i < 3840; i += 256) s_cw[i] = conv_w[i];

    int s  = tid >> 6;
    int lt = tid & 63;
    int b  = blockIdx.x * FB_SAMPLES + s;

    if (lt < 27) {
        float v;
        if (lt < 16)      v = car_tbl[(size_t)car_idx[b] * 16 + lt];
        else if (lt < 19) v = week_tbl[week_idx[b] * 3 + (lt - 16)];
        else              v = time_tbl[time_idx[b] * 8 + (lt - 19)];
        s_emb[s][lt] = tanhf(v);
    }
    for (int i = lt; i < 120; i += 64) {
        int t = i / 12, k = i % 12;
        float v;
        if (k < 8) v = region_tbl[(size_t)region_idx[b * 10 + t] * 8 + k];
        else       v = poi_tbl[poi_idx[b * 10 + t] * 4 + (k - 8)];
        s_rp[s][t][k] = v;
    }
    __syncthreads();

    for (int i = lt; i < 400; i += 64) {
        int t = i / 40, j = i % 40;
        float acc;
        if (j < 32) {
            acc = b_rp[j];
            #pragma unroll
            for (int k = 0; k < 12; k++) acc += s_rp[s][t][k] * W_rp[k * 32 + j];
        } else {
            int j2 = j - 32;
            acc = b_co[j2] + coords[(size_t)(b * 10 + t) * 2 + 0] * W_co[j2]
                           + coords[(size_t)(b * 10 + t) * 2 + 1] * W_co[8 + j2];
        }
        s_nv[s][t][j] = acc;
    }
    __syncthreads();

    for (int i = lt; i < 256; i += 64) {
        int t = i >> 5, o = i & 31;
        float acc = conv_b[o];
        #pragma unroll
        for (int dt = 0; dt < 3; dt++)
            #pragma unroll
            for (int c = 0; c < 40; c++)
                acc += s_nv[s][t + dt][c] * s_cw[(dt * 40 + c) * 32 + o];
        acc = acc > 0.f ? acc : expm1f(acc);
        Xp[(size_t)(b * 8 + t) * 64 + o] = (__bf16)acc;
    }
    for (int i = lt; i < 216; i += 64) {
        int t = i / 27, j = i % 27;
        Xp[(size_t)(b * 8 + t) * 64 + 32 + j] = (__bf16)s_emb[s][j];
    }
    for (int i = lt; i < 40; i += 64) {
        int t = i / 5, j = i % 5;
        Xp[(size_t)(b * 8 + t) * 64 + 59 + j] = (__bf16)0.f;
    }
}

// ---------------------------------------------------------------------------
// Fused LSTM step v2:
//  - weights pre-swizzled in B-fragment order -> direct global->reg loads
//  - wave-per-gate (no duplicated B reads)
//  - double-buffered A LDS tile, 1 barrier per K-tile
//  - pointwise epilogue via per-m-frag LDS gate exchange
// A = [A1 | A2] (K1 = width of A1). W-frags: [kt][gate][nf 0..15][lane][8].
// Block: 256 thr = 4 waves (wave g = gate g), tile M=128, 64 cols/gate.
// Grid: (4, B/128).
// ---------------------------------------------------------------------------
#define AST 40   // LDS A-row stride in bf16 (80B -> 2-way banks, free)
__global__ __launch_bounds__(256, 2) void lstm_fused(
    const __bf16* __restrict__ A1, int lda1, int K1,
    const __bf16* __restrict__ A2, int lda2,
    const __bf16* __restrict__ WS,
    const float* __restrict__ bias, float* __restrict__ cst,
    __bf16* __restrict__ hb,
    int KT, int is_t0)
{
    __shared__ __align__(16) unsigned char smem[2 * 128 * AST * 2];  // 20.5 KB
    __bf16* As = (__bf16*)smem;                 // [2][128*AST]
    float*  GL = (float*)smem;                  // [4][16][68] (17.4 KB)

    int tid = threadIdx.x;
    int bm  = blockIdx.y * 128;
    int bnf = blockIdx.x * 4;                   // n-frag base within gate
    int bn  = blockIdx.x * 64;                  // col base within gate
    int l   = tid & 63;
    int g   = tid >> 6;                         // wave == gate
    int fr  = l & 15;
    int fo  = (l >> 4) * 8;

    f32x4 acc[8][4] = {};                       // [m-frag][n-frag]

    int s_row  = tid >> 1;
    int s_half = tid & 1;

    auto asrc = [&](int kt) -> const __bf16* {
        int k0 = kt * 32;
        if (k0 < K1) return A1 + (size_t)(bm + s_row) * lda1 + k0 + s_half * 16;
        return A2 + (size_t)(bm + s_row) * lda2 + (k0 - K1) + s_half * 16;
    };
    const __bf16* wbase = WS + ((size_t)g * 16 + bnf) * 512 + (size_t)l * 8;
    // strides in elements: per kt = 32768, per n-frag = 512

    // ---- prologue: stage A(0), load B(0)
    {
        const __bf16* s = asrc(0);
        bf16x8 v0 = *(const bf16x8*)s;
        bf16x8 v1 = *(const bf16x8*)(s + 8);
        *(bf16x8*)&As[s_row * AST + s_half * 16]     = v0;
        *(bf16x8*)&As[s_row * AST + s_half * 16 + 8] = v1;
    }
    bf16x8 bcur[4];
    #pragma unroll
    for (int j = 0; j < 4; j++) bcur[j] = *(const bf16x8*)(wbase + j * 512);

    for (int kt = 0; kt < KT; kt++) {
        int cb = kt & 1;
        bf16x8 bnxt[4], an0, an1;
        if (kt + 1 < KT) {
            const __bf16* s = asrc(kt + 1);
            an0 = *(const bf16x8*)s;
            an1 = *(const bf16x8*)(s + 8);
            const __bf16* wb = wbase + (size_t)(kt + 1) * 32768;
            #pragma unroll
            for (int j = 0; j < 4; j++) bnxt[j] = *(const bf16x8*)(wb + j * 512);
        }
        __syncthreads();
        bf16x8 af[8];
        #pragma unroll
        for (int mf = 0; mf < 8; mf++)
            af[mf] = *(bf16x8*)&As[cb * 128 * AST + (mf * 16 + fr) * AST + fo];
        #pragma unroll
        for (int mf = 0; mf < 8; mf++)
            #pragma unroll
            for (int j = 0; j < 4; j++)
                acc[mf][j] = __builtin_amdgcn_mfma_f32_16x16x32_bf16(
                    af[mf], bcur[j], acc[mf][j], 0, 0, 0);
        if (kt + 1 < KT) {
            *(bf16x8*)&As[(cb ^ 1) * 128 * AST + s_row * AST + s_half * 16]     = an0;
            *(bf16x8*)&As[(cb ^ 1) * 128 * AST + s_row * AST + s_half * 16 + 8] = an1;
            #pragma unroll
            for (int j = 0; j < 4; j++) bcur[j] = bnxt[j];
        }
    }

    // ---- epilogue: per-m-frag gate exchange through LDS + pointwise
    int rbase = (l >> 4) * 4;
    int prow  = tid >> 4;            // 0..15
    int pcol  = (tid & 15) * 4;      // 0..60
    // bias regs (same for every m-frag): 4 gates x 4 cols
    f32x4 bs[4];
    #pragma unroll
    for (int gg = 0; gg < 4; gg++)
        bs[gg] = *(const f32x4*)&bias[gg * 256 + bn + pcol];

    for (int mf = 0; mf < 8; mf++) {
        __syncthreads();   // previous users of smem done
        #pragma unroll
        for (int j = 0; j < 4; j++)
            #pragma unroll
            for (int e = 0; e < 4; e++)
                GL[(g * 16 + rbase + e) * 68 + j * 16 + fr] = acc[mf][j][e];
        __syncthreads();

        size_t moff = ((size_t)bm + mf * 16 + prow) * 256 + bn + pcol;
        f32x4 gi = *(f32x4*)&GL[(0 * 16 + prow) * 68 + pcol];
        f32x4 gf = *(f32x4*)&GL[(1 * 16 + prow) * 68 + pcol];
        f32x4 gg = *(f32x4*)&GL[(2 * 16 + prow) * 68 + pcol];
        f32x4 go = *(f32x4*)&GL[(3 * 16 + prow) * 68 + pcol];
        f32x4 cold = {0.f, 0.f, 0.f, 0.f};
        if (!is_t0) cold = *(f32x4*)&cst[moff];
        f32x4 cn;
        union { unsigned short u[4]; unsigned long long v; } hx;
        #pragma unroll
        for (int q = 0; q < 4; q++) {
            float i_ = fsigm(gi[q] + bs[0][q]);
            float f_ = fsigm(gf[q] + bs[1][q]);
            float g_ = ftanh(gg[q] + bs[2][q]);
            float o_ = fsigm(go[q] + bs[3][q]);
            float c_ = f_ * cold[q] + i_ * g_;
            cn[q] = c_;
            float h_ = o_ * ftanh(c_);
            __bf16 hv = (__bf16)h_;
            hx.u[q] = *(unsigned short*)&hv;
        }
        *(f32x4*)&cst[moff] = cn;
        *(unsigned long long*)&hb[moff] = hx.v;
    }
}

// ---------------------------------------------------------------------------
// Head GEMM via MFMA: out[16384][512] = h1b @ Wcomb + bcomb (bf16 in, f32 out)
// WS frags: [kt 0..7][nf 0..31][lane][8]. Block: 4 waves, M=128, 256 cols.
// Grid: (2, 128).
// ---------------------------------------------------------------------------
__global__ __launch_bounds__(256, 2) void head_mfma(
    const __bf16* __restrict__ A,          // [16384][256]
    const __bf16* __restrict__ WS,
    const float* __restrict__ bias, float* __restrict__ out)
{
    __shared__ __align__(16) __bf16 As[2][128 * AST];

    int tid = threadIdx.x;
    int bm  = blockIdx.y * 128;
    int l   = tid & 63;
    int wv  = tid >> 6;
    int fr  = l & 15;
    int fo  = (l >> 4) * 8;
    int nfb = blockIdx.x * 16 + wv * 4;

    f32x4 acc[8][4] = {};

    int s_row  = tid >> 1;
    int s_half = tid & 1;
    const __bf16* abase = A + (size_t)(bm + s_row) * 256 + s_half * 16;
    const __bf16* wbase = WS + (size_t)nfb * 512 + (size_t)l * 8;
    // strides: per kt = 32*64*8 = 16384, per n-frag = 512

    {
        bf16x8 v0 = *(const bf16x8*)abase;
        bf16x8 v1 = *(const bf16x8*)(abase + 8);
        *(bf16x8*)&As[0][s_row * AST + s_half * 16]     = v0;
        *(bf16x8*)&As[0][s_row * AST + s_half * 16 + 8] = v1;
    }
    bf16x8 bcur[4];
    #pragma unroll
    for (int j = 0; j < 4; j++) bcur[j] = *(const bf16x8*)(wbase + j * 512);

    for (int kt = 0; kt < 8; kt++) {
        int cb = kt & 1;
        bf16x8 bnxt[4], an0, an1;
        if (kt + 1 < 8) {
            const __bf16* s = abase + (kt + 1) * 32;
            an0 = *(const bf16x8*)s;
            an1 = *(const bf16x8*)(s + 8);
            const __bf16* wb = wbase + (size_t)(kt + 1) * 16384;
            #pragma unroll
            for (int j = 0; j < 4; j++) bnxt[j] = *(const bf16x8*)(wb + j * 512);
        }
        __syncthreads();
        bf16x8 af[8];
        #pragma unroll
        for (int mf = 0; mf < 8; mf++)
            af[mf] = *(bf16x8*)&As[cb][(mf * 16 + fr) * AST + fo];
        #pragma unroll
        for (int mf = 0; mf < 8; mf++)
            #pragma unroll
            for (int j = 0; j < 4; j++)
                acc[mf][j] = __builtin_amdgcn_mfma_f32_16x16x32_bf16(
                    af[mf], bcur[j], acc[mf][j], 0, 0, 0);
        if (kt + 1 < 8) {
            *(bf16x8*)&As[cb ^ 1][s_row * AST + s_half * 16]     = an0;
            *(bf16x8*)&As[cb ^ 1][s_row * AST + s_half * 16 + 8] = an1;
            #pragma unroll
            for (int j = 0; j < 4; j++) bcur[j] = bnxt[j];
        }
    }

    int rbase = (l >> 4) * 4;
    #pragma unroll
    for (int mf = 0; mf < 8; mf++) {
        #pragma unroll
        for (int j = 0; j < 4; j++) {
            int n = (nfb + j) * 16 + fr;
            float bv = bias[n];
            #pragma unroll
            for (int e = 0; e < 4; e++) {
                size_t m = (size_t)bm + mf * 16 + rbase + e;
                out[m * 512 + n] = acc[mf][j][e] + bv;
            }
        }
    }
}

// ---------------------------------------------------------------------------
// Split-K fp32 GEMM (weight collapse) + reduce
// ---------------------------------------------------------------------------
__global__ __launch_bounds__(256) void gemm_nn_sk(
    const float* __restrict__ A, int lda, const float* __restrict__ Bm, int ldb,
    float* __restrict__ P, int M, int N, int K)
{
    __shared__ float As[16][68];
    __shared__ float Bs[16][68];
    int tid = threadIdx.x;
    int tx = tid & 15, ty = tid >> 4;
    int bm = blockIdx.y * 64, bn = blockIdx.x * 64;
    int klen = K / SK;
    int kbeg = blockIdx.z * klen;

    float acc[4][4] = {};

    for (int k0 = kbeg; k0 < kbeg + klen; k0 += 16) {
        for (int i = tid; i < 1024; i += 256) {
            int k = i & 15, m = i >> 4;
            As[k][m] = A[(size_t)(bm + m) * lda + k0 + k];
        }
        for (int i = tid; i < 1024; i += 256) {
            int n = i & 63, k = i >> 6;
            Bs[k][n] = Bm[(size_t)(k0 + k) * ldb + bn + n];
        }
        __syncthreads();
        #pragma unroll
        for (int kk = 0; kk < 16; kk++) {
            float4 a = *(const float4*)&As[kk][ty * 4];
            float4 b = *(const float4*)&Bs[kk][tx * 4];
            float av[4] = {a.x, a.y, a.z, a.w};
            float bv[4] = {b.x, b.y, b.z, b.w};
            #pragma unroll
            for (int i = 0; i < 4; i++)
                #pragma unroll
                for (int j = 0; j < 4; j++)
                    acc[i][j] += av[i] * bv[j];
        }
        __syncthreads();
    }

    float* Pd = P + (size_t)blockIdx.z * M * N;
    #pragma unroll
    for (int i = 0; i < 4; i++) {
        int m = bm + ty * 4 + i;
        #pragma unroll
        for (int j = 0; j < 4; j++) {
            int n = bn + tx * 4 + j;
            Pd[(size_t)m * N + n] = acc[i][j];
        }
    }
}

__global__ __launch_bounds__(256) void reduce_sk(
    const float* __restrict__ P, int MN, float* __restrict__ C)
{
    int i = blockIdx.x * 256 + threadIdx.x;
    if (i >= MN) return;
    float a = 0.f;
    #pragma unroll
    for (int s = 0; s < SK; s++) a += P[(size_t)s * MN + i];
    C[i] = a;
}

// ---------------------------------------------------------------------------
// vecmat: outv[n] = bias[n] + sum_k v[k] * M[k*ldb + n]
// ---------------------------------------------------------------------------
__global__ __launch_bounds__(256) void vecmat(
    const float* __restrict__ v, const float* __restrict__ M, int ldb, int K,
    const float* __restrict__ bias, float* __restrict__ outv)
{
    __shared__ float red[4][64];
    int l = threadIdx.x & 63;
    int w = threadIdx.x >> 6;
    int n = blockIdx.x * 64 + l;
    int kpw = K >> 2;
    int k0 = w * kpw;

    float p[8] = {};
    for (int k = k0; k < k0 + kpw; k += 8) {
        #pragma unroll
        for (int u = 0; u < 8; u++)
            p[u] += v[k + u] * M[(size_t)(k + u) * ldb + n];
    }
    red[w][l] = ((p[0] + p[1]) + (p[2] + p[3])) + ((p[4] + p[5]) + (p[6] + p[7]));
    __syncthreads();
    if (w == 0)
        outv[n] = red[0][l] + red[1][l] + red[2][l] + red[3][l]
                + (bias ? bias[n] : 0.f);
}

// ---------------------------------------------------------------------------
// Small helpers / packers
// ---------------------------------------------------------------------------
__global__ void add_vec(const float* __restrict__ a, const float* __restrict__ b,
                        float* __restrict__ c, int n)
{
    int i = blockIdx.x * 256 + threadIdx.x;
    if (i < n) c[i] = a[i] + b[i];
}

// WS0 frag layout [kt 0..9][g][nf 0..15][lane][8] from [Wih0|pad5|Whh0]
__global__ void pack_w0_swz(const float* __restrict__ Wih, const float* __restrict__ Whh,
                            __bf16* __restrict__ WS)
{
    int idx = blockIdx.x * 256 + threadIdx.x;
    if (idx >= 10 * 4 * 16 * 64 * 8) return;
    int e  = idx & 7;
    int l  = (idx >> 3) & 63;
    int nf = (idx >> 9) & 15;
    int g  = (idx >> 13) & 3;
    int kt = idx >> 15;
    int n_row = g * 256 + nf * 16 + (l & 15);
    int k = kt * 32 + ((l >> 4) * 8) + e;
    float v = (k < 59) ? Wih[(size_t)n_row * 59 + k]
            : (k < 64) ? 0.f
                       : Whh[(size_t)n_row * 256 + (k - 64)];
    WS[idx] = (__bf16)v;
}

// WS1 frag layout [kt 0..15][g][nf 0..15][lane][8] from [Wih1|Whh1]
__global__ void pack_w1_swz(const float* __restrict__ Wih, const float* __restrict__ Whh,
                            __bf16* __restrict__ WS)
{
    int idx = blockIdx.x * 256 + threadIdx.x;
    if (idx >= 16 * 4 * 16 * 64 * 8) return;
    int e  = idx & 7;
    int l  = (idx >> 3) & 63;
    int nf = (idx >> 9) & 15;
    int g  = (idx >> 13) & 3;
    int kt = idx >> 15;
    int n_row = g * 256 + nf * 16 + (l & 15);
    int k = kt * 32 + ((l >> 4) * 8) + e;
    float v = (k < 256) ? Wih[(size_t)n_row * 256 + k]
                        : Whh[(size_t)n_row * 256 + (k - 256)];
    WS[idx] = (__bf16)v;
}

// WSH frag layout [kt 0..7][nf 0..31][lane][8] from Wcomb f32 [256][512]
__global__ void pack_head_swz(const float* __restrict__ Wc, __bf16* __restrict__ WS)
{
    int idx = blockIdx.x * 256 + threadIdx.x;
    if (idx >= 8 * 32 * 64 * 8) return;
    int e  = idx & 7;
    int l  = (idx >> 3) & 63;
    int nf = (idx >> 9) & 31;
    int kt = idx >> 14;
    int n = nf * 16 + (l & 15);
    int k = kt * 32 + ((l >> 4) * 8) + e;
    WS[idx] = (__bf16)Wc[(size_t)k * 512 + n];
}

// ---------------------------------------------------------------------------
extern "C" void kernel_launch(void* const* d_in, const int* in_sizes, int n_in,
                              void* d_out, int out_size, void* d_ws, size_t ws_size,
                              hipStream_t stream)
{
    const int*   region_idx = (const int*)d_in[0];
    const int*   poi_idx    = (const int*)d_in[1];
    const int*   car_idx    = (const int*)d_in[2];
    const int*   week_idx   = (const int*)d_in[3];
    const int*   time_idx   = (const int*)d_in[4];
    const float* coords     = (const float*)d_in[5];
    const float* region_tbl = (const float*)d_in[6];
    const float* poi_tbl    = (const float*)d_in[7];
    const float* car_tbl    = (const float*)d_in[8];
    const float* week_tbl   = (const float*)d_in[9];
    const float* time_tbl   = (const float*)d_in[10];
    const float* W_rp   = (const float*)d_in[11];
    const float* b_rp   = (const float*)d_in[12];
    const float* W_co   = (const float*)d_in[13];
    const float* b_co   = (const float*)d_in[14];
    const float* conv_w = (const float*)d_in[15];
    const float* conv_b = (const float*)d_in[16];
    const float* Wih0 = (const float*)d_in[17];
    const float* Whh0 = (const float*)d_in[18];
    const float* bih0 = (const float*)d_in[19];
    const float* bhh0 = (const float*)d_in[20];
    const float* Wih1 = (const float*)d_in[21];
    const float* Whh1 = (const float*)d_in[22];
    const float* bih1 = (const float*)d_in[23];
    const float* bhh1 = (const float*)d_in[24];
    const float* W1 = (const float*)d_in[25];
    const float* b1 = (const float*)d_in[26];
    const float* W2 = (const float*)d_in[27];
    const float* b2 = (const float*)d_in[28];
    const float* W3 = (const float*)d_in[29];
    const float* b3 = (const float*)d_in[30];
    float* out = (float*)d_out;

    // ---- workspace layout (~88 MB) ----
    char* ws = (char*)d_ws;
    size_t off = 0;
    auto alloc = [&](size_t bytes) -> char* {
        char* p = ws + off;
        off = (off + bytes + 255) & ~(size_t)255;
        return p;
    };
    __bf16* Xp   = (__bf16*)alloc((size_t)B_SZ * 8 * 64 * 2);   // 16.8 MB
    __bf16* h0b  = (__bf16*)alloc((size_t)B_SZ * HID * 2);      // 8.4 MB
    __bf16* h1b  = (__bf16*)alloc((size_t)B_SZ * HID * 2);      // 8.4 MB
    float*  c0   = (float*)alloc((size_t)B_SZ * HID * 4);       // 16.8 MB
    float*  c1   = (float*)alloc((size_t)B_SZ * HID * 4);       // 16.8 MB
    __bf16* WS0  = (__bf16*)alloc((size_t)10 * 4 * 16 * 64 * 8 * 2);  // 640 KB
    __bf16* WS1  = (__bf16*)alloc((size_t)16 * 4 * 16 * 64 * 8 * 2);  // 1 MB
    __bf16* WSH  = (__bf16*)alloc((size_t)8 * 32 * 64 * 8 * 2);       // 256 KB
    float*  T1    = (float*)alloc(256 * 1024 * 4);
    float*  tb1   = (float*)alloc(1024 * 4);
    float*  Wcomb = (float*)alloc(256 * 512 * 4);
    float*  bcomb = (float*)alloc(512 * 4);
    float*  bias0 = (float*)alloc(1024 * 4);
    float*  bias1 = (float*)alloc(1024 * 4);
    float*  Psk   = (float*)alloc((size_t)SK * 256 * 1024 * 4); // 16.8 MB
    (void)ws_size;

    // ---- weight prep ----
    pack_w0_swz<<<1280, 256, 0, stream>>>(Wih0, Whh0, WS0);
    pack_w1_swz<<<2048, 256, 0, stream>>>(Wih1, Whh1, WS1);
    add_vec<<<4, 256, 0, stream>>>(bih0, bhh0, bias0, 1024);
    add_vec<<<4, 256, 0, stream>>>(bih1, bhh1, bias1, 1024);

    // ---- collapse head: Wcomb = W1@W2@W3, bcomb = (b1@W2+b2)@W3+b3 ----
    gemm_nn_sk<<<dim3(16, 4, SK), 256, 0, stream>>>(W1, 512, W2, 1024, Psk, 256, 1024, 512);
    reduce_sk<<<(256 * 1024 + 255) / 256, 256, 0, stream>>>(Psk, 256 * 1024, T1);
    vecmat<<<16, 256, 0, stream>>>(b1, W2, 1024, 512, b2, tb1);
    gemm_nn_sk<<<dim3(8, 4, SK), 256, 0, stream>>>(T1, 1024, W3, 512, Psk, 256, 512, 1024);
    reduce_sk<<<(256 * 512 + 255) / 256, 256, 0, stream>>>(Psk, 256 * 512, Wcomb);
    vecmat<<<8, 256, 0, stream>>>(tb1, W3, 512, 1024, b3, bcomb);
    pack_head_swz<<<512, 256, 0, stream>>>(Wcomb, WSH);

    // ---- features -> Xp bf16 ----
    feature_kernel<<<B_SZ / FB_SAMPLES, 256, 0, stream>>>(
        region_idx, poi_idx, car_idx, week_idx, time_idx, coords,
        region_tbl, poi_tbl, car_tbl, week_tbl, time_tbl,
        W_rp, b_rp, W_co, b_co, conv_w, conv_b, Xp);

    // ---- LSTM: both layers interleaved per timestep ----
    dim3 lstm_grid(4, B_SZ / 128);
    for (int t = 0; t < T_CONV; t++) {
        lstm_fused<<<lstm_grid, 256, 0, stream>>>(
            Xp + (size_t)t * 64, 8 * 64, 64,
            h0b, HID,
            WS0, bias0, c0, h0b,
            t == 0 ? 2 : 10, t == 0);

        lstm_fused<<<lstm_grid, 256, 0, stream>>>(
            h0b, HID, 256,
            h1b, HID,
            WS1, bias1, c1, h1b,
            t == 0 ? 8 : 16, t == 0);
    }

    // ---- head: out = h1b @ Wcomb + bcomb ----
    head_mfma<<<dim3(2, 128), 256, 0, stream>>>(h1b, WSH, bcomb, out);
}

// Round 8
// 605.785 us; speedup vs baseline: 7.1443x; 7.1443x over previous
//
#include <hip/hip_runtime.h>
#include <hip/hip_bf16.h>
#include <math.h>

#define B_SZ 16384
#define T_CONV 8
#define HID 256
#define SK 16   // split-K slices for the weight-collapse GEMMs

typedef __bf16 bf16x8 __attribute__((ext_vector_type(8)));
typedef float f32x4 __attribute__((ext_vector_type(4)));

__device__ __forceinline__ float fsigm(float x) { return 1.f / (1.f + __expf(-x)); }
__device__ __forceinline__ float ftanh(float x) {
    float t = __expf(-2.f * fabsf(x));
    float r = (1.f - t) / (1.f + t);
    return x >= 0.f ? r : -r;
}

// ---------------------------------------------------------------------------
// Feature kernel: embeddings -> nv -> conv(elu) -> Xp (B*8, 64) bf16, padded
// ---------------------------------------------------------------------------
#define FB_SAMPLES 4
__global__ __launch_bounds__(256) void feature_kernel(
    const int* __restrict__ region_idx, const int* __restrict__ poi_idx,
    const int* __restrict__ car_idx, const int* __restrict__ week_idx,
    const int* __restrict__ time_idx, const float* __restrict__ coords,
    const float* __restrict__ region_tbl, const float* __restrict__ poi_tbl,
    const float* __restrict__ car_tbl, const float* __restrict__ week_tbl,
    const float* __restrict__ time_tbl, const float* __restrict__ W_rp,
    const float* __restrict__ b_rp, const float* __restrict__ W_co,
    const float* __restrict__ b_co, const float* __restrict__ conv_w,
    const float* __restrict__ conv_b, __bf16* __restrict__ Xp)
{
    __shared__ float s_cw[3 * 40 * 32];
    __shared__ float s_nv[FB_SAMPLES][10][40];
    __shared__ float s_emb[FB_SAMPLES][27];
    __shared__ float s_rp[FB_SAMPLES][10][12];

    int tid = threadIdx.x;
    for (int i = tid; i < 3840; i += 256) s_cw[i] = conv_w[i];

    int s  = tid >> 6;
    int lt = tid & 63;
    int b  = blockIdx.x * FB_SAMPLES + s;

    if (lt < 27) {
        float v;
        if (lt < 16)      v = car_tbl[(size_t)car_idx[b] * 16 + lt];
        else if (lt < 19) v = week_tbl[week_idx[b] * 3 + (lt - 16)];
        else              v = time_tbl[time_idx[b] * 8 + (lt - 19)];
        s_emb[s][lt] = tanhf(v);
    }
    for (int i = lt; i < 120; i += 64) {
        int t = i / 12, k = i % 12;
        float v;
        if (k < 8) v = region_tbl[(size_t)region_idx[b * 10 + t] * 8 + k];
        else       v = poi_tbl[poi_idx[b * 10 + t] * 4 + (k - 8)];
        s_rp[s][t][k] = v;
    }
    __syncthreads();

    for (int i = lt; i < 400; i += 64) {
        int t = i / 40, j = i % 40;
        float acc;
        if (j < 32) {
            acc = b_rp[j];
            #pragma unroll
            for (int k = 0; k < 12; k++) acc += s_rp[s][t][k] * W_rp[k * 32 + j];
        } else {
            int j2 = j - 32;
            acc = b_co[j2] + coords[(size_t)(b * 10 + t) * 2 + 0] * W_co[j2]
                           + coords[(size_t)(b * 10 + t) * 2 + 1] * W_co[8 + j2];
        }
        s_nv[s][t][j] = acc;
    }
    __syncthreads();

    for (int i = lt; i < 256; i += 64) {
        int t = i >> 5, o = i & 31;
        float acc = conv_b[o];
        #pragma unroll
        for (int dt = 0; dt < 3; dt++)
            #pragma unroll
            for (int c = 0; c < 40; c++)
                acc += s_nv[s][t + dt][c] * s_cw[(dt * 40 + c) * 32 + o];
        acc = acc > 0.f ? acc : expm1f(acc);
        Xp[(size_t)(b * 8 + t) * 64 + o] = (__bf16)acc;
    }
    for (int i = lt; i < 216; i += 64) {
        int t = i / 27, j = i % 27;
        Xp[(size_t)(b * 8 + t) * 64 + 32 + j] = (__bf16)s_emb[s][j];
    }
    for (int i = lt; i < 40; i += 64) {
        int t = i / 5, j = i % 5;
        Xp[(size_t)(b * 8 + t) * 64 + 59 + j] = (__bf16)0.f;
    }
}

// ---------------------------------------------------------------------------
// Fused LSTM step v2 (spill-fixed): epilogue mf loop fully unrolled so acc
// indexing is static (rule #20 — runtime-indexed ext_vector arrays spill).
// ---------------------------------------------------------------------------
#define AST 40   // LDS A-row stride in bf16 (80B -> 2-way banks, free)
__global__ __launch_bounds__(256, 2) void lstm_fused(
    const __bf16* __restrict__ A1, int lda1, int K1,
    const __bf16* __restrict__ A2, int lda2,
    const __bf16* __restrict__ WS,
    const float* __restrict__ bias, float* __restrict__ cst,
    __bf16* __restrict__ hb,
    int KT, int is_t0)
{
    __shared__ __align__(16) unsigned char smem[2 * 128 * AST * 2];  // 20.5 KB
    __bf16* As = (__bf16*)smem;                 // [2][128*AST]
    float*  GL = (float*)smem;                  // [4][16][68] (17.4 KB)

    int tid = threadIdx.x;
    int bm  = blockIdx.y * 128;
    int bnf = blockIdx.x * 4;                   // n-frag base within gate
    int bn  = blockIdx.x * 64;                  // col base within gate
    int l   = tid & 63;
    int g   = tid >> 6;                         // wave == gate
    int fr  = l & 15;
    int fo  = (l >> 4) * 8;

    f32x4 acc[8][4] = {};                       // [m-frag][n-frag]

    int s_row  = tid >> 1;
    int s_half = tid & 1;

    auto asrc = [&](int kt) -> const __bf16* {
        int k0 = kt * 32;
        if (k0 < K1) return A1 + (size_t)(bm + s_row) * lda1 + k0 + s_half * 16;
        return A2 + (size_t)(bm + s_row) * lda2 + (k0 - K1) + s_half * 16;
    };
    const __bf16* wbase = WS + ((size_t)g * 16 + bnf) * 512 + (size_t)l * 8;
    // strides in elements: per kt = 32768, per n-frag = 512

    // ---- prologue: stage A(0), load B(0)
    {
        const __bf16* s = asrc(0);
        bf16x8 v0 = *(const bf16x8*)s;
        bf16x8 v1 = *(const bf16x8*)(s + 8);
        *(bf16x8*)&As[s_row * AST + s_half * 16]     = v0;
        *(bf16x8*)&As[s_row * AST + s_half * 16 + 8] = v1;
    }
    bf16x8 bcur[4];
    #pragma unroll
    for (int j = 0; j < 4; j++) bcur[j] = *(const bf16x8*)(wbase + j * 512);

    for (int kt = 0; kt < KT; kt++) {
        int cb = kt & 1;
        bf16x8 bnxt[4], an0, an1;
        if (kt + 1 < KT) {
            const __bf16* s = asrc(kt + 1);
            an0 = *(const bf16x8*)s;
            an1 = *(const bf16x8*)(s + 8);
            const __bf16* wb = wbase + (size_t)(kt + 1) * 32768;
            #pragma unroll
            for (int j = 0; j < 4; j++) bnxt[j] = *(const bf16x8*)(wb + j * 512);
        }
        __syncthreads();
        bf16x8 af[8];
        #pragma unroll
        for (int mf = 0; mf < 8; mf++)
            af[mf] = *(bf16x8*)&As[cb * 128 * AST + (mf * 16 + fr) * AST + fo];
        #pragma unroll
        for (int mf = 0; mf < 8; mf++)
            #pragma unroll
            for (int j = 0; j < 4; j++)
                acc[mf][j] = __builtin_amdgcn_mfma_f32_16x16x32_bf16(
                    af[mf], bcur[j], acc[mf][j], 0, 0, 0);
        if (kt + 1 < KT) {
            *(bf16x8*)&As[(cb ^ 1) * 128 * AST + s_row * AST + s_half * 16]     = an0;
            *(bf16x8*)&As[(cb ^ 1) * 128 * AST + s_row * AST + s_half * 16 + 8] = an1;
            #pragma unroll
            for (int j = 0; j < 4; j++) bcur[j] = bnxt[j];
        }
    }

    // ---- epilogue: per-m-frag gate exchange through LDS + pointwise
    // FULLY UNROLLED so acc[mf][j] is always statically indexed (no scratch).
    int rbase = (l >> 4) * 4;
    int prow  = tid >> 4;            // 0..15
    int pcol  = (tid & 15) * 4;      // 0..60
    f32x4 bs[4];
    #pragma unroll
    for (int gg = 0; gg < 4; gg++)
        bs[gg] = *(const f32x4*)&bias[gg * 256 + bn + pcol];

    #pragma unroll
    for (int mf = 0; mf < 8; mf++) {
        __syncthreads();   // previous users of smem done
        #pragma unroll
        for (int j = 0; j < 4; j++)
            #pragma unroll
            for (int e = 0; e < 4; e++)
                GL[(g * 16 + rbase + e) * 68 + j * 16 + fr] = acc[mf][j][e];
        __syncthreads();

        size_t moff = ((size_t)bm + mf * 16 + prow) * 256 + bn + pcol;
        f32x4 gi = *(f32x4*)&GL[(0 * 16 + prow) * 68 + pcol];
        f32x4 gf = *(f32x4*)&GL[(1 * 16 + prow) * 68 + pcol];
        f32x4 gg = *(f32x4*)&GL[(2 * 16 + prow) * 68 + pcol];
        f32x4 go = *(f32x4*)&GL[(3 * 16 + prow) * 68 + pcol];
        f32x4 cold = {0.f, 0.f, 0.f, 0.f};
        if (!is_t0) cold = *(f32x4*)&cst[moff];
        f32x4 cn;
        union { unsigned short u[4]; unsigned long long v; } hx;
        #pragma unroll
        for (int q = 0; q < 4; q++) {
            float i_ = fsigm(gi[q] + bs[0][q]);
            float f_ = fsigm(gf[q] + bs[1][q]);
            float g_ = ftanh(gg[q] + bs[2][q]);
            float o_ = fsigm(go[q] + bs[3][q]);
            float c_ = f_ * cold[q] + i_ * g_;
            cn[q] = c_;
            float h_ = o_ * ftanh(c_);
            __bf16 hv = (__bf16)h_;
            hx.u[q] = *(unsigned short*)&hv;
        }
        *(f32x4*)&cst[moff] = cn;
        *(unsigned long long*)&hb[moff] = hx.v;
    }
}

// ---------------------------------------------------------------------------
// Head GEMM via MFMA: out[16384][512] = h1b @ Wcomb + bcomb (bf16 in, f32 out)
// ---------------------------------------------------------------------------
__global__ __launch_bounds__(256, 2) void head_mfma(
    const __bf16* __restrict__ A,          // [16384][256]
    const __bf16* __restrict__ WS,
    const float* __restrict__ bias, float* __restrict__ out)
{
    __shared__ __align__(16) __bf16 As[2][128 * AST];

    int tid = threadIdx.x;
    int bm  = blockIdx.y * 128;
    int l   = tid & 63;
    int wv  = tid >> 6;
    int fr  = l & 15;
    int fo  = (l >> 4) * 8;
    int nfb = blockIdx.x * 16 + wv * 4;

    f32x4 acc[8][4] = {};

    int s_row  = tid >> 1;
    int s_half = tid & 1;
    const __bf16* abase = A + (size_t)(bm + s_row) * 256 + s_half * 16;
    const __bf16* wbase = WS + (size_t)nfb * 512 + (size_t)l * 8;

    {
        bf16x8 v0 = *(const bf16x8*)abase;
        bf16x8 v1 = *(const bf16x8*)(abase + 8);
        *(bf16x8*)&As[0][s_row * AST + s_half * 16]     = v0;
        *(bf16x8*)&As[0][s_row * AST + s_half * 16 + 8] = v1;
    }
    bf16x8 bcur[4];
    #pragma unroll
    for (int j = 0; j < 4; j++) bcur[j] = *(const bf16x8*)(wbase + j * 512);

    #pragma unroll
    for (int kt = 0; kt < 8; kt++) {
        int cb = kt & 1;
        bf16x8 bnxt[4], an0, an1;
        if (kt + 1 < 8) {
            const __bf16* s = abase + (kt + 1) * 32;
            an0 = *(const bf16x8*)s;
            an1 = *(const bf16x8*)(s + 8);
            const __bf16* wb = wbase + (size_t)(kt + 1) * 16384;
            #pragma unroll
            for (int j = 0; j < 4; j++) bnxt[j] = *(const bf16x8*)(wb + j * 512);
        }
        __syncthreads();
        bf16x8 af[8];
        #pragma unroll
        for (int mf = 0; mf < 8; mf++)
            af[mf] = *(bf16x8*)&As[cb][(mf * 16 + fr) * AST + fo];
        #pragma unroll
        for (int mf = 0; mf < 8; mf++)
            #pragma unroll
            for (int j = 0; j < 4; j++)
                acc[mf][j] = __builtin_amdgcn_mfma_f32_16x16x32_bf16(
                    af[mf], bcur[j], acc[mf][j], 0, 0, 0);
        if (kt + 1 < 8) {
            *(bf16x8*)&As[cb ^ 1][s_row * AST + s_half * 16]     = an0;
            *(bf16x8*)&As[cb ^ 1][s_row * AST + s_half * 16 + 8] = an1;
            #pragma unroll
            for (int j = 0; j < 4; j++) bcur[j] = bnxt[j];
        }
    }

    int rbase = (l >> 4) * 4;
    #pragma unroll
    for (int mf = 0; mf < 8; mf++) {
        #pragma unroll
        for (int j = 0; j < 4; j++) {
            int n = (nfb + j) * 16 + fr;
            float bv = bias[n];
            #pragma unroll
            for (int e = 0; e < 4; e++) {
                size_t m = (size_t)bm + mf * 16 + rbase + e;
                out[m * 512 + n] = acc[mf][j][e] + bv;
            }
        }
    }
}

// ---------------------------------------------------------------------------
// Split-K fp32 GEMM (weight collapse) + reduce
// ---------------------------------------------------------------------------
__global__ __launch_bounds__(256) void gemm_nn_sk(
    const float* __restrict__ A, int lda, const float* __restrict__ Bm, int ldb,
    float* __restrict__ P, int M, int N, int K)
{
    __shared__ float As[16][68];
    __shared__ float Bs[16][68];
    int tid = threadIdx.x;
    int tx = tid & 15, ty = tid >> 4;
    int bm = blockIdx.y * 64, bn = blockIdx.x * 64;
    int klen = K / SK;
    int kbeg = blockIdx.z * klen;

    float acc[4][4] = {};

    for (int k0 = kbeg; k0 < kbeg + klen; k0 += 16) {
        for (int i = tid; i < 1024; i += 256) {
            int k = i & 15, m = i >> 4;
            As[k][m] = A[(size_t)(bm + m) * lda + k0 + k];
        }
        for (int i = tid; i < 1024; i += 256) {
            int n = i & 63, k = i >> 6;
            Bs[k][n] = Bm[(size_t)(k0 + k) * ldb + bn + n];
        }
        __syncthreads();
        #pragma unroll
        for (int kk = 0; kk < 16; kk++) {
            float4 a = *(const float4*)&As[kk][ty * 4];
            float4 b = *(const float4*)&Bs[kk][tx * 4];
            float av[4] = {a.x, a.y, a.z, a.w};
            float bv[4] = {b.x, b.y, b.z, b.w};
            #pragma unroll
            for (int i = 0; i < 4; i++)
                #pragma unroll
                for (int j = 0; j < 4; j++)
                    acc[i][j] += av[i] * bv[j];
        }
        __syncthreads();
    }

    float* Pd = P + (size_t)blockIdx.z * M * N;
    #pragma unroll
    for (int i = 0; i < 4; i++) {
        int m = bm + ty * 4 + i;
        #pragma unroll
        for (int j = 0; j < 4; j++) {
            int n = bn + tx * 4 + j;
            Pd[(size_t)m * N + n] = acc[i][j];
        }
    }
}

__global__ __launch_bounds__(256) void reduce_sk(
    const float* __restrict__ P, int MN, float* __restrict__ C)
{
    int i = blockIdx.x * 256 + threadIdx.x;
    if (i >= MN) return;
    float a = 0.f;
    #pragma unroll
    for (int s = 0; s < SK; s++) a += P[(size_t)s * MN + i];
    C[i] = a;
}

// ---------------------------------------------------------------------------
// vecmat: outv[n] = bias[n] + sum_k v[k] * M[k*ldb + n]
// ---------------------------------------------------------------------------
__global__ __launch_bounds__(256) void vecmat(
    const float* __restrict__ v, const float* __restrict__ M, int ldb, int K,
    const float* __restrict__ bias, float* __restrict__ outv)
{
    __shared__ float red[4][64];
    int l = threadIdx.x & 63;
    int w = threadIdx.x >> 6;
    int n = blockIdx.x * 64 + l;
    int kpw = K >> 2;
    int k0 = w * kpw;

    float p[8] = {};
    for (int k = k0; k < k0 + kpw; k += 8) {
        #pragma unroll
        for (int u = 0; u < 8; u++)
            p[u] += v[k + u] * M[(size_t)(k + u) * ldb + n];
    }
    red[w][l] = ((p[0] + p[1]) + (p[2] + p[3])) + ((p[4] + p[5]) + (p[6] + p[7]));
    __syncthreads();
    if (w == 0)
        outv[n] = red[0][l] + red[1][l] + red[2][l] + red[3][l]
                + (bias ? bias[n] : 0.f);
}

// ---------------------------------------------------------------------------
// Small helpers / packers
// ---------------------------------------------------------------------------
__global__ void add_vec(const float* __restrict__ a, const float* __restrict__ b,
                        float* __restrict__ c, int n)
{
    int i = blockIdx.x * 256 + threadIdx.x;
    if (i < n) c[i] = a[i] + b[i];
}

// WS0 frag layout [kt 0..9][g][nf 0..15][lane][8] from [Wih0|pad5|Whh0]
__global__ void pack_w0_swz(const float* __restrict__ Wih, const float* __restrict__ Whh,
                            __bf16* __restrict__ WS)
{
    int idx = blockIdx.x * 256 + threadIdx.x;
    if (idx >= 10 * 4 * 16 * 64 * 8) return;
    int e  = idx & 7;
    int l  = (idx >> 3) & 63;
    int nf = (idx >> 9) & 15;
    int g  = (idx >> 13) & 3;
    int kt = idx >> 15;
    int n_row = g * 256 + nf * 16 + (l & 15);
    int k = kt * 32 + ((l >> 4) * 8) + e;
    float v = (k < 59) ? Wih[(size_t)n_row * 59 + k]
            : (k < 64) ? 0.f
                       : Whh[(size_t)n_row * 256 + (k - 64)];
    WS[idx] = (__bf16)v;
}

// WS1 frag layout [kt 0..15][g][nf 0..15][lane][8] from [Wih1|Whh1]
__global__ void pack_w1_swz(const float* __restrict__ Wih, const float* __restrict__ Whh,
                            __bf16* __restrict__ WS)
{
    int idx = blockIdx.x * 256 + threadIdx.x;
    if (idx >= 16 * 4 * 16 * 64 * 8) return;
    int e  = idx & 7;
    int l  = (idx >> 3) & 63;
    int nf = (idx >> 9) & 15;
    int g  = (idx >> 13) & 3;
    int kt = idx >> 15;
    int n_row = g * 256 + nf * 16 + (l & 15);
    int k = kt * 32 + ((l >> 4) * 8) + e;
    float v = (k < 256) ? Wih[(size_t)n_row * 256 + k]
                        : Whh[(size_t)n_row * 256 + (k - 256)];
    WS[idx] = (__bf16)v;
}

// WSH frag layout [kt 0..7][nf 0..31][lane][8] from Wcomb f32 [256][512]
__global__ void pack_head_swz(const float* __restrict__ Wc, __bf16* __restrict__ WS)
{
    int idx = blockIdx.x * 256 + threadIdx.x;
    if (idx >= 8 * 32 * 64 * 8) return;
    int e  = idx & 7;
    int l  = (idx >> 3) & 63;
    int nf = (idx >> 9) & 31;
    int kt = idx >> 14;
    int n = nf * 16 + (l & 15);
    int k = kt * 32 + ((l >> 4) * 8) + e;
    WS[idx] = (__bf16)Wc[(size_t)k * 512 + n];
}

// ---------------------------------------------------------------------------
extern "C" void kernel_launch(void* const* d_in, const int* in_sizes, int n_in,
                              void* d_out, int out_size, void* d_ws, size_t ws_size,
                              hipStream_t stream)
{
    const int*   region_idx = (const int*)d_in[0];
    const int*   poi_idx    = (const int*)d_in[1];
    const int*   car_idx    = (const int*)d_in[2];
    const int*   week_idx   = (const int*)d_in[3];
    const int*   time_idx   = (const int*)d_in[4];
    const float* coords     = (const float*)d_in[5];
    const float* region_tbl = (const float*)d_in[6];
    const float* poi_tbl    = (const float*)d_in[7];
    const float* car_tbl    = (const float*)d_in[8];
    const float* week_tbl   = (const float*)d_in[9];
    const float* time_tbl   = (const float*)d_in[10];
    const float* W_rp   = (const float*)d_in[11];
    const float* b_rp   = (const float*)d_in[12];
    const float* W_co   = (const float*)d_in[13];
    const float* b_co   = (const float*)d_in[14];
    const float* conv_w = (const float*)d_in[15];
    const float* conv_b = (const float*)d_in[16];
    const float* Wih0 = (const float*)d_in[17];
    const float* Whh0 = (const float*)d_in[18];
    const float* bih0 = (const float*)d_in[19];
    const float* bhh0 = (const float*)d_in[20];
    const float* Wih1 = (const float*)d_in[21];
    const float* Whh1 = (const float*)d_in[22];
    const float* bih1 = (const float*)d_in[23];
    const float* bhh1 = (const float*)d_in[24];
    const float* W1 = (const float*)d_in[25];
    const float* b1 = (const float*)d_in[26];
    const float* W2 = (const float*)d_in[27];
    const float* b2 = (const float*)d_in[28];
    const float* W3 = (const float*)d_in[29];
    const float* b3 = (const float*)d_in[30];
    float* out = (float*)d_out;

    // ---- workspace layout (~88 MB) ----
    char* ws = (char*)d_ws;
    size_t off = 0;
    auto alloc = [&](size_t bytes) -> char* {
        char* p = ws + off;
        off = (off + bytes + 255) & ~(size_t)255;
        return p;
    };
    __bf16* Xp   = (__bf16*)alloc((size_t)B_SZ * 8 * 64 * 2);   // 16.8 MB
    __bf16* h0b  = (__bf16*)alloc((size_t)B_SZ * HID * 2);      // 8.4 MB
    __bf16* h1b  = (__bf16*)alloc((size_t)B_SZ * HID * 2);      // 8.4 MB
    float*  c0   = (float*)alloc((size_t)B_SZ * HID * 4);       // 16.8 MB
    float*  c1   = (float*)alloc((size_t)B_SZ * HID * 4);       // 16.8 MB
    __bf16* WS0  = (__bf16*)alloc((size_t)10 * 4 * 16 * 64 * 8 * 2);  // 640 KB
    __bf16* WS1  = (__bf16*)alloc((size_t)16 * 4 * 16 * 64 * 8 * 2);  // 1 MB
    __bf16* WSH  = (__bf16*)alloc((size_t)8 * 32 * 64 * 8 * 2);       // 256 KB
    float*  T1    = (float*)alloc(256 * 1024 * 4);
    float*  tb1   = (float*)alloc(1024 * 4);
    float*  Wcomb = (float*)alloc(256 * 512 * 4);
    float*  bcomb = (float*)alloc(512 * 4);
    float*  bias0 = (float*)alloc(1024 * 4);
    float*  bias1 = (float*)alloc(1024 * 4);
    float*  Psk   = (float*)alloc((size_t)SK * 256 * 1024 * 4); // 16.8 MB
    (void)ws_size;

    // ---- weight prep ----
    pack_w0_swz<<<1280, 256, 0, stream>>>(Wih0, Whh0, WS0);
    pack_w1_swz<<<2048, 256, 0, stream>>>(Wih1, Whh1, WS1);
    add_vec<<<4, 256, 0, stream>>>(bih0, bhh0, bias0, 1024);
    add_vec<<<4, 256, 0, stream>>>(bih1, bhh1, bias1, 1024);

    // ---- collapse head: Wcomb = W1@W2@W3, bcomb = (b1@W2+b2)@W3+b3 ----
    gemm_nn_sk<<<dim3(16, 4, SK), 256, 0, stream>>>(W1, 512, W2, 1024, Psk, 256, 1024, 512);
    reduce_sk<<<(256 * 1024 + 255) / 256, 256, 0, stream>>>(Psk, 256 * 1024, T1);
    vecmat<<<16, 256, 0, stream>>>(b1, W2, 1024, 512, b2, tb1);
    gemm_nn_sk<<<dim3(8, 4, SK), 256, 0, stream>>>(T1, 1024, W3, 512, Psk, 256, 512, 1024);
    reduce_sk<<<(256 * 512 + 255) / 256, 256, 0, stream>>>(Psk, 256 * 512, Wcomb);
    vecmat<<<8, 256, 0, stream>>>(tb1, W3, 512, 1024, b3, bcomb);
    pack_head_swz<<<512, 256, 0, stream>>>(Wcomb, WSH);

    // ---- features -> Xp bf16 ----
    feature_kernel<<<B_SZ / FB_SAMPLES, 256, 0, stream>>>(
        region_idx, poi_idx, car_idx, week_idx, time_idx, coords,
        region_tbl, poi_tbl, car_tbl, week_tbl, time_tbl,
        W_rp, b_rp, W_co, b_co, conv_w, conv_b, Xp);

    // ---- LSTM: both layers interleaved per timestep ----
    dim3 lstm_grid(4, B_SZ / 128);
    for (int t = 0; t < T_CONV; t++) {
        lstm_fused<<<lstm_grid, 256, 0, stream>>>(
            Xp + (size_t)t * 64, 8 * 64, 64,
            h0b, HID,
            WS0, bias0, c0, h0b,
            t == 0 ? 2 : 10, t == 0);

        lstm_fused<<<lstm_grid, 256, 0, stream>>>(
            h0b, HID, 256,
            h1b, HID,
            WS1, bias1, c1, h1b,
            t == 0 ? 8 : 16, t == 0);
    }

    // ---- head: out = h1b @ Wcomb + bcomb ----
    head_mfma<<<dim3(2, 128), 256, 0, stream>>>(h1b, WSH, bcomb, out);
}